// Round 2
// baseline (9612.829 us; speedup 1.0000x reference)
//
#include <hip/hip_runtime.h>

// ScannedRNN (flax GRUCell with per-step carry reset), T=512, B=128, H=512.
// R1: gi = X@Wi+bi as one f16-MFMA GEMM (unchanged from R0); recurrence as ONE
// persistent kernel looping 512 steps with a per-b-group software barrier.
// h exchange: ping-pong f16 global buffers; fp32 master h kept in registers.

typedef _Float16 f16;
typedef _Float16 f16x8 __attribute__((ext_vector_type(8)));
typedef float f32x4 __attribute__((ext_vector_type(4)));

#define TT 512
#define BB 128
#define HH 512
#define H3 1536
#define TBR 65536  // TT*BB rows

// ---------------------------------------------------------------- k_prep ----
__global__ __launch_bounds__(256) void k_prep(
    const float* __restrict__ Wi, const float* __restrict__ Wh,
    const float* __restrict__ h0,
    f16* __restrict__ WiT, f16* __restrict__ WhT,
    f16* __restrict__ h16init, int* __restrict__ cnt) {
  int idx = blockIdx.x * 256 + threadIdx.x;
  if (idx < HH * H3) {
    int n = idx >> 9;         // 0..1535 (output col)
    int k = idx & (HH - 1);   // 0..511
    WiT[idx] = (f16)Wi[(size_t)k * H3 + n];
    WhT[idx] = (f16)Wh[(size_t)k * H3 + n];
  }
  if (idx < BB * HH) h16init[idx] = (f16)h0[idx];
  if (idx < 4 * 32) cnt[idx] = 0;  // barrier counters (padded 128B apart)
}

// ------------------------------------------------------------- k_gemm_gi ----
// gi[i,j] = sum_k x[i,k]*Wi[k,j] + bi[j]; 64x64 tile, f16 MFMA 16x16x32.
__global__ __launch_bounds__(256) void k_gemm_gi(
    const float* __restrict__ x, const f16* __restrict__ WiT,
    const float* __restrict__ bi, f16* __restrict__ gi) {
  __shared__ __align__(16) f16 As[64 * 48];
  __shared__ __align__(16) f16 Bs[64 * 48];
  const int tid = threadIdx.x;
  const int lane = tid & 63;
  const int w = tid >> 6;
  const int i0 = blockIdx.x * 64;
  const int j0 = blockIdx.y * 64;
  const int mw = (w & 1) * 32;
  const int nw = (w >> 1) * 32;

  f32x4 acc[2][2] = {};
  const int srow = tid >> 2;
  const int skp = (tid & 3) * 8;
  const int fr = lane & 15;
  const int fq8 = (lane >> 4) * 8;

  for (int kb = 0; kb < 16; ++kb) {
    const int k0 = kb * 32;
    const float* xp = x + (size_t)(i0 + srow) * HH + k0 + skp;
    float4 v0 = *(const float4*)xp;
    float4 v1 = *(const float4*)(xp + 4);
    f16x8 a8;
    a8[0] = (f16)v0.x; a8[1] = (f16)v0.y; a8[2] = (f16)v0.z; a8[3] = (f16)v0.w;
    a8[4] = (f16)v1.x; a8[5] = (f16)v1.y; a8[6] = (f16)v1.z; a8[7] = (f16)v1.w;
    *(f16x8*)&As[srow * 48 + skp] = a8;
    *(f16x8*)&Bs[srow * 48 + skp] =
        *(const f16x8*)(WiT + (size_t)(j0 + srow) * HH + k0 + skp);
    __syncthreads();
    f16x8 af0 = *(const f16x8*)&As[(mw + fr) * 48 + fq8];
    f16x8 af1 = *(const f16x8*)&As[(mw + 16 + fr) * 48 + fq8];
    f16x8 bf0 = *(const f16x8*)&Bs[(nw + fr) * 48 + fq8];
    f16x8 bf1 = *(const f16x8*)&Bs[(nw + 16 + fr) * 48 + fq8];
    acc[0][0] = __builtin_amdgcn_mfma_f32_16x16x32_f16(af0, bf0, acc[0][0], 0, 0, 0);
    acc[0][1] = __builtin_amdgcn_mfma_f32_16x16x32_f16(af0, bf1, acc[0][1], 0, 0, 0);
    acc[1][0] = __builtin_amdgcn_mfma_f32_16x16x32_f16(af1, bf0, acc[1][0], 0, 0, 0);
    acc[1][1] = __builtin_amdgcn_mfma_f32_16x16x32_f16(af1, bf1, acc[1][1], 0, 0, 0);
    __syncthreads();
  }
  const int trow = (lane >> 4) * 4;
  for (int mi = 0; mi < 2; ++mi)
    for (int ni = 0; ni < 2; ++ni)
      for (int r = 0; r < 4; ++r) {
        int row = mw + mi * 16 + trow + r;
        int col = nw + ni * 16 + fr;
        int j = j0 + col;
        gi[(size_t)(i0 + row) * H3 + j] = (f16)(acc[mi][ni][r] + bi[j]);
      }
}

// ---------------------------------------------------------------- k_scan ----
// Persistent: grid (4 bt x 16 jt) = 64 blocks, 256 thr. Block owns 32 b-rows
// x 32 j-cols. Wave w: m-half = w&1, 16-col group c0 = (w>>1)*16, all 3 gates.
// Barrier: per-bt monotonic counter, 16 arrivals/step.
__global__ __launch_bounds__(256) void k_scan(
    const int* __restrict__ resets, const f16* __restrict__ WhT,
    const f16* __restrict__ gi, const float* __restrict__ bhn,
    const float* __restrict__ h0, float* __restrict__ out,
    f16* __restrict__ hb0, f16* __restrict__ hb1, int* __restrict__ cnt) {
  __shared__ __align__(16) f16 As[32 * 520];
  const int tid = threadIdx.x;
  const int lane = tid & 63;
  const int w = tid >> 6;
  const int bt = blockIdx.x;          // 0..3
  const int b0 = bt * 32;
  const int j0 = blockIdx.y * 32;
  const int m = w & 1;
  const int c0 = (w >> 1) * 16;
  const int fr = lane & 15;
  const int fq8 = (lane >> 4) * 8;
  const int trow = (lane >> 4) * 4;
  const int jj = j0 + c0 + fr;        // my output col
  const int bb = b0 + m * 16 + trow;  // my output row base (+r)
  const float bh = bhn[jj];
  int* mycnt = cnt + bt * 32;         // 128B-padded counter

  float hm[4];
#pragma unroll
  for (int r = 0; r < 4; ++r) hm[r] = h0[(size_t)(bb + r) * HH + jj];

  const f16* wp0 = WhT + ((size_t)(0 * HH + jj)) * HH + fq8;
  const f16* wp1 = WhT + ((size_t)(1 * HH + jj)) * HH + fq8;
  const f16* wp2 = WhT + ((size_t)(2 * HH + jj)) * HH + fq8;

  const int srow = tid >> 3;          // 0..31
  const int skc = (tid & 7) * 64;     // 0..448

  f16* hb[2] = {hb0, hb1};            // step t: read hb[(t+1)&1], write hb[t&1]

  for (int t = 0; t < TT; ++t) {
    // --- gi prefetch + resets (independent of barrier) ---
    const size_t gb = ((size_t)t * BB + bb) * H3 + jj;
    f16 g0[4], g1[4], g2[4];
#pragma unroll
    for (int r = 0; r < 4; ++r) {
      g0[r] = gi[gb + (size_t)r * H3];
      g1[r] = gi[gb + (size_t)r * H3 + HH];
      g2[r] = gi[gb + (size_t)r * H3 + 2 * HH];
    }
    const int* rst = resets + t * BB;
    int myrs[4];
#pragma unroll
    for (int r = 0; r < 4; ++r) myrs[r] = rst[bb + r];
    const int srs = rst[b0 + srow];

    // --- wait for step t-1's h writes (all 16 jt blocks of this bt) ---
    if (t > 0) {
      if (tid == 0) {
        while (__hip_atomic_load(mycnt, __ATOMIC_RELAXED,
                                 __HIP_MEMORY_SCOPE_AGENT) < 16 * t) {
          __builtin_amdgcn_s_sleep(1);
        }
      }
      __syncthreads();
      __threadfence();  // acquire: invalidate stale L1/L2 before reading hin
    }

    // --- stage h (reset-zeroed) -> LDS ---
    const f16* hin = hb[(t + 1) & 1];
    f16* hout = hb[t & 1];
    {
      const f16x8* src = (const f16x8*)(hin + (size_t)(b0 + srow) * HH + skc);
      f16x8* dst = (f16x8*)&As[srow * 520 + skc];
      if (srs) {
        f16x8 z = {};
#pragma unroll
        for (int u = 0; u < 8; ++u) dst[u] = z;
      } else {
#pragma unroll
        for (int u = 0; u < 8; ++u) dst[u] = src[u];
      }
    }
    __syncthreads();

    // --- gh MFMA: 3 gates x 16 k-steps (B-frags streamed from L2) ---
    f32x4 a0 = {}, a1 = {}, a2 = {};
#pragma unroll 4
    for (int kb = 0; kb < 16; ++kb) {
      const int k0 = kb * 32;
      f16x8 af = *(const f16x8*)&As[(m * 16 + fr) * 520 + k0 + fq8];
      f16x8 b0f = *(const f16x8*)(wp0 + k0);
      f16x8 b1f = *(const f16x8*)(wp1 + k0);
      f16x8 b2f = *(const f16x8*)(wp2 + k0);
      a0 = __builtin_amdgcn_mfma_f32_16x16x32_f16(af, b0f, a0, 0, 0, 0);
      a1 = __builtin_amdgcn_mfma_f32_16x16x32_f16(af, b1f, a1, 0, 0, 0);
      a2 = __builtin_amdgcn_mfma_f32_16x16x32_f16(af, b2f, a2, 0, 0, 0);
    }

    // --- fused gate math + h update (fp32 master in regs) ---
#pragma unroll
    for (int r = 0; r < 4; ++r) {
      const int b = bb + r;
      const float hp = myrs[r] ? 0.f : hm[r];
      const float rr = 1.f / (1.f + __expf(-((float)g0[r] + a0[r])));
      const float zz = 1.f / (1.f + __expf(-((float)g1[r] + a1[r])));
      const float nn = tanhf((float)g2[r] + rr * (a2[r] + bh));
      const float hnew = (1.f - zz) * nn + zz * hp;
      hm[r] = hnew;
      out[((size_t)t * BB + b) * HH + jj] = hnew;
      hout[(size_t)b * HH + jj] = (f16)hnew;
    }

    // --- release + arrive ---
    __threadfence();   // flush my h writes to agent-visible point (cross-XCD)
    __syncthreads();   // all threads of block fenced
    if (tid == 0) atomicAdd(mycnt, 1);
  }
}

// ---------------------------------------------------------------------------
extern "C" void kernel_launch(void* const* d_in, const int* in_sizes, int n_in,
                              void* d_out, int out_size, void* d_ws, size_t ws_size,
                              hipStream_t stream) {
  const float* x = (const float*)d_in[0];
  const int* resets = (const int*)d_in[1];
  const float* Wi = (const float*)d_in[2];
  const float* bi = (const float*)d_in[3];
  const float* Wh = (const float*)d_in[4];
  const float* bhn = (const float*)d_in[5];
  const float* h0 = (const float*)d_in[6];
  float* out = (float*)d_out;

  char* ws = (char*)d_ws;
  size_t off = 0;
  f16* gi = (f16*)(ws + off);   off += (size_t)TBR * H3 * sizeof(f16);   // 201.3 MB
  f16* WiT = (f16*)(ws + off);  off += (size_t)HH * H3 * sizeof(f16);    // 1.5 MB
  f16* WhT = (f16*)(ws + off);  off += (size_t)HH * H3 * sizeof(f16);    // 1.5 MB
  f16* hb0 = (f16*)(ws + off);  off += (size_t)BB * HH * sizeof(f16);
  f16* hb1 = (f16*)(ws + off);  off += (size_t)BB * HH * sizeof(f16);
  int* cnt = (int*)(ws + off);  off += 4 * 32 * sizeof(int);
  (void)ws_size; (void)in_sizes; (void)n_in; (void)out_size;

  // initial h (f16 mirror) lives in hb1: step 0 reads hb[(0+1)&1] = hb1
  k_prep<<<dim3((HH * H3) / 256), 256, 0, stream>>>(Wi, Wh, h0, WiT, WhT, hb1, cnt);
  k_gemm_gi<<<dim3(TBR / 64, H3 / 64), 256, 0, stream>>>(x, WiT, bi, gi);
  k_scan<<<dim3(4, 16), 256, 0, stream>>>(resets, WhT, gi, bhn, h0, out, hb0, hb1, cnt);
}

// Round 3
// 2717.457 us; speedup vs baseline: 3.5374x; 3.5374x over previous
//
#include <hip/hip_runtime.h>

// ScannedRNN (flax GRUCell with per-step carry reset), T=512, B=128, H=512.
// R2: reset-segmented chunk-parallel scan. T split into 64 chunks of L=8.
// Phase 1: run all chunks from h=0 (exact from first in-chunk reset onward)
//          as 8 dense [8192x512]@[512x1536] MFMA macro-steps.
// Phase 2: per-b sequential chunk-boundary propagation (no cross-block sync);
//          full 8-step propagate only for rare no-reset chunks.
// Phase 3: prefix fixup (positions before first reset) as gather-GEMMs over
//          an fr-sorted row list, 8 launches with device-side early exit.

typedef _Float16 f16;
typedef _Float16 f16x8 __attribute__((ext_vector_type(8)));
typedef float f32x4 __attribute__((ext_vector_type(4)));

#define TT 512
#define BB 128
#define HH 512
#define H3 1536
#define TBR 65536                     // TT*BB rows
#define NC 64                         // chunks
#define CL 8                          // chunk length
#define NR 8192                       // NC*BB rows of chunk-state
static const size_t PL = (size_t)TBR * HH;  // gi plane stride (elements)

__device__ __forceinline__ float sigf(float x) { return 1.f / (1.f + __expf(-x)); }

// ---------------------------------------------------------------- k_prep ----
// Weight transposes to [n][k] f16 + per-(c,b) first-reset fr + bucket counts.
__global__ __launch_bounds__(256) void k_prep(
    const float* __restrict__ Wi, const float* __restrict__ Wh,
    const int* __restrict__ resets,
    f16* __restrict__ WiT, f16* __restrict__ WhT,
    int* __restrict__ fr, int* __restrict__ cnt) {
  int idx = blockIdx.x * 256 + threadIdx.x;
  if (idx < HH * H3) {
    int n = idx >> 9;         // output col 0..1535
    int k = idx & (HH - 1);   // 0..511
    WiT[idx] = (f16)Wi[(size_t)k * H3 + n];
    WhT[idx] = (f16)Wh[(size_t)k * H3 + n];
  }
  if (idx < NR) {
    int c = idx >> 7, b = idx & 127;
    int f = CL;
    for (int s = CL - 1; s >= 0; --s)
      if (resets[(c * CL + s) * BB + b]) f = s;
    fr[idx] = f;
    atomicAdd(&cnt[f], 1);    // cnt[0..8] bucket counts (pre-zeroed)
  }
}

// ---------------------------------------------------------------- k_sort ----
// st[f] = #rows with fr > f (descending-fr bucket starts). cnt layout:
// [0..8]=bc, [16..24]=st (st[s]=cnt_gt[s] for phase3), [32..40]=wk (scatter).
__global__ void k_sort(int* __restrict__ cnt) {
  int st = 0;
  cnt[16 + 8] = 0;
  for (int f = 7; f >= 0; --f) {
    st += cnt[f + 1];
    cnt[16 + f] = st;
  }
  for (int f = 1; f <= 8; ++f) cnt[32 + f] = cnt[16 + f];
}

__global__ __launch_bounds__(256) void k_scatter(
    const int* __restrict__ fr, int* __restrict__ cnt, int* __restrict__ list) {
  int idx = blockIdx.x * 256 + threadIdx.x;
  if (idx < NR) {
    int f = fr[idx];
    if (f >= 1) {
      int pos = atomicAdd(&cnt[32 + f], 1);
      list[pos] = idx;
    }
  }
}

// ------------------------------------------------------------- k_gemm_gi ----
// gi[plane p][i][jj] = sum_k x[i,k]*Wi[k, p*512+jj] + bi; 64x64 tile.
__global__ __launch_bounds__(256) void k_gemm_gi(
    const float* __restrict__ x, const f16* __restrict__ WiT,
    const float* __restrict__ bi, f16* __restrict__ gi) {
  __shared__ __align__(16) f16 As[64 * 48];
  __shared__ __align__(16) f16 Bs[64 * 48];
  const int tid = threadIdx.x;
  const int lane = tid & 63;
  const int w = tid >> 6;
  const int i0 = blockIdx.x * 64;
  const int j0 = blockIdx.y * 64;
  const int mw = (w & 1) * 32;
  const int nw = (w >> 1) * 32;

  f32x4 acc[2][2] = {};
  const int srow = tid >> 2;
  const int skp = (tid & 3) * 8;
  const int fr = lane & 15;
  const int fq8 = (lane >> 4) * 8;

  for (int kb = 0; kb < 16; ++kb) {
    const int k0 = kb * 32;
    const float* xp = x + (size_t)(i0 + srow) * HH + k0 + skp;
    float4 v0 = *(const float4*)xp;
    float4 v1 = *(const float4*)(xp + 4);
    f16x8 a8;
    a8[0] = (f16)v0.x; a8[1] = (f16)v0.y; a8[2] = (f16)v0.z; a8[3] = (f16)v0.w;
    a8[4] = (f16)v1.x; a8[5] = (f16)v1.y; a8[6] = (f16)v1.z; a8[7] = (f16)v1.w;
    *(f16x8*)&As[srow * 48 + skp] = a8;
    *(f16x8*)&Bs[srow * 48 + skp] =
        *(const f16x8*)(WiT + (size_t)(j0 + srow) * HH + k0 + skp);
    __syncthreads();
    f16x8 af0 = *(const f16x8*)&As[(mw + fr) * 48 + fq8];
    f16x8 af1 = *(const f16x8*)&As[(mw + 16 + fr) * 48 + fq8];
    f16x8 bf0 = *(const f16x8*)&Bs[(nw + fr) * 48 + fq8];
    f16x8 bf1 = *(const f16x8*)&Bs[(nw + 16 + fr) * 48 + fq8];
    acc[0][0] = __builtin_amdgcn_mfma_f32_16x16x32_f16(af0, bf0, acc[0][0], 0, 0, 0);
    acc[0][1] = __builtin_amdgcn_mfma_f32_16x16x32_f16(af0, bf1, acc[0][1], 0, 0, 0);
    acc[1][0] = __builtin_amdgcn_mfma_f32_16x16x32_f16(af1, bf0, acc[1][0], 0, 0, 0);
    acc[1][1] = __builtin_amdgcn_mfma_f32_16x16x32_f16(af1, bf1, acc[1][1], 0, 0, 0);
    __syncthreads();
  }
  const int trow = (lane >> 4) * 4;
  for (int mi = 0; mi < 2; ++mi)
    for (int ni = 0; ni < 2; ++ni)
      for (int r = 0; r < 4; ++r) {
        int row = mw + mi * 16 + trow + r;
        int col = nw + ni * 16 + fr;
        int j = j0 + col;                 // 0..1535
        int p = j >> 9, jj = j & 511;
        gi[(size_t)p * PL + (size_t)(i0 + row) * HH + jj] =
            (f16)(acc[mi][ni][r] + bi[j]);
      }
}

// ---------------------------------------------------------------- k_step0 ----
// Macro-step s=0: h_prev = 0 for all chunk-start rows -> elementwise gates.
// Writes out[t=c*8] (garbage for prefix rows, fixed by phase 3) and hA
// (zeroed where reset at s=1).
__global__ __launch_bounds__(256) void k_step0(
    const int* __restrict__ resets, const f16* __restrict__ gi,
    const float* __restrict__ bhn, float* __restrict__ out,
    f16* __restrict__ hA) {
  int gid = blockIdx.x * 256 + threadIdx.x;     // NR*64 units of 8
  int row = gid >> 6;                           // 0..8191 (c*128+b)
  int c8 = (gid & 63) * 8;
  int c = row >> 7, b = row & 127;
  size_t girow = (size_t)c * 1024 + b;          // t=c*8 -> t*128+b
  const f16x8 g0 = *(const f16x8*)(gi + girow * HH + c8);
  const f16x8 g1 = *(const f16x8*)(gi + PL + girow * HH + c8);
  const f16x8 g2 = *(const f16x8*)(gi + 2 * PL + girow * HH + c8);
  const int z1 = resets[(c * CL + 1) * BB + b];
  float4 o[2];
  f16x8 hn;
#pragma unroll
  for (int u = 0; u < 8; ++u) {
    float r = sigf((float)g0[u]);
    float z = sigf((float)g1[u]);
    float n = tanhf((float)g2[u] + r * bhn[c8 + u]);
    float h = (1.f - z) * n;
    ((float*)o)[u] = h;
    hn[u] = z1 ? (f16)0.f : (f16)h;
  }
  *(float4*)(out + girow * HH + c8) = o[0];
  *(float4*)(out + girow * HH + c8 + 4) = o[1];
  *(f16x8*)(hA + (size_t)row * HH + c8) = hn;
}

// --------------------------------------------------------------- k_phase1 ----
// Macro-step s (1..7): [8192x512] @ WhT[512x1536] (3 gates) + fused gates.
// Grid (64 chunks, 8 j-tiles of 64). Reads h from hrd, writes hwr (ping-pong
// to avoid same-launch RAW across j-tile blocks of the same chunk).
__global__ __launch_bounds__(256, 2) void k_phase1(
    int s, const int* __restrict__ resets, const f16* __restrict__ WhT,
    const f16* __restrict__ gi, const float* __restrict__ bhn,
    float* __restrict__ out, const f16* __restrict__ hrd,
    f16* __restrict__ hwr) {
  __shared__ __align__(16) f16 As[128 * 40];   // pad 40 halfs -> 2-way banks
  __shared__ __align__(16) f16 Bs[192 * 40];
  const int tid = threadIdx.x;
  const int lane = tid & 63;
  const int w = tid >> 6;
  const int c = blockIdx.x;
  const int j0 = blockIdx.y * 64;
  const int t = c * CL + s;
  const int wm = (w & 1) * 64;
  const int wn = (w >> 1) * 32;
  const int fr = lane & 15;
  const int q8 = (lane >> 4) * 8;

  f32x4 acc[3][4][2] = {};

  for (int kb = 0; kb < 16; ++kb) {
    const int k0 = kb * 32;
#pragma unroll
    for (int uu = 0; uu < 2; ++uu) {      // A: 128 rows x 4 octets
      int u = tid + uu * 256;
      int row = u >> 2, oc = (u & 3) * 8;
      *(f16x8*)&As[row * 40 + oc] =
          *(const f16x8*)(hrd + ((size_t)(c * BB + row)) * HH + k0 + oc);
    }
#pragma unroll
    for (int uu = 0; uu < 3; ++uu) {      // B: 192 rows (3 gates x 64 cols)
      int u = tid + uu * 256;
      int row = u >> 2, oc = (u & 3) * 8;
      int g = row >> 6, j = j0 + (row & 63);
      *(f16x8*)&Bs[row * 40 + oc] =
          *(const f16x8*)(WhT + ((size_t)(g * HH + j)) * HH + k0 + oc);
    }
    __syncthreads();
    f16x8 af[4];
#pragma unroll
    for (int mi = 0; mi < 4; ++mi)
      af[mi] = *(const f16x8*)&As[(wm + mi * 16 + fr) * 40 + q8];
    f16x8 bf[3][2];
#pragma unroll
    for (int g = 0; g < 3; ++g)
#pragma unroll
      for (int ni = 0; ni < 2; ++ni)
        bf[g][ni] = *(const f16x8*)&Bs[(g * 64 + wn + ni * 16 + fr) * 40 + q8];
#pragma unroll
    for (int g = 0; g < 3; ++g)
#pragma unroll
      for (int mi = 0; mi < 4; ++mi)
#pragma unroll
        for (int ni = 0; ni < 2; ++ni)
          acc[g][mi][ni] = __builtin_amdgcn_mfma_f32_16x16x32_f16(
              af[mi], bf[g][ni], acc[g][mi][ni], 0, 0, 0);
    __syncthreads();
  }

  const int trow = (lane >> 4) * 4;
#pragma unroll
  for (int mi = 0; mi < 4; ++mi)
#pragma unroll
    for (int ni = 0; ni < 2; ++ni) {
      const int j = j0 + wn + ni * 16 + fr;
      const float bh = bhn[j];
#pragma unroll
      for (int r = 0; r < 4; ++r) {
        const int b = wm + mi * 16 + trow + r;     // 0..127
        const size_t girow = (size_t)c * 1024 + (size_t)s * BB + b;
        const float gr = (float)gi[girow * HH + j];
        const float gz = (float)gi[PL + girow * HH + j];
        const float gn = (float)gi[2 * PL + girow * HH + j];
        const float hp = (float)hrd[((size_t)(c * BB + b)) * HH + j];
        const float rr = sigf(gr + acc[0][mi][ni][r]);
        const float zz = sigf(gz + acc[1][mi][ni][r]);
        const float nn = tanhf(gn + rr * (acc[2][mi][ni][r] + bh));
        const float hnew = (1.f - zz) * nn + zz * hp;
        out[girow * HH + j] = hnew;
        int zr = (s < 7) ? resets[(t + 1) * BB + b] : 0;
        hwr[((size_t)(c * BB + b)) * HH + j] = zr ? (f16)0.f : (f16)hnew;
      }
    }
}

// --------------------------------------------------------------- k_phase2 ----
// One block per batch row b; sequential over 64 chunks; no cross-block sync.
// Writes entering-h per chunk (hin, f16); rare no-reset chunks propagate 8
// GRU steps on VALU (also writing out for those positions).
__global__ __launch_bounds__(256) void k_phase2(
    const int* __restrict__ fr, const f16* __restrict__ hend,
    const f16* __restrict__ WhT, const f16* __restrict__ gi,
    const float* __restrict__ bhn, const float* __restrict__ h0,
    float* __restrict__ out, f16* __restrict__ hin) {
  __shared__ float hs[HH];
  __shared__ float gh[H3];
  const int b = blockIdx.x;
  const int tid = threadIdx.x;
  for (int i = tid; i < HH; i += 256) hs[i] = h0[(size_t)b * HH + i];
  __syncthreads();
  for (int c = 0; c < NC; ++c) {
    const int row = c * BB + b;
    for (int i = tid; i < HH; i += 256)
      hin[(size_t)row * HH + i] = (f16)hs[i];
    if (fr[row] < CL) {
      __syncthreads();
      for (int i = tid; i < HH; i += 256)
        hs[i] = (float)hend[(size_t)row * HH + i];
      __syncthreads();
    } else {
      // propagate 8 steps (no resets in this chunk)
      for (int s = 0; s < CL; ++s) {
        const size_t girow = (size_t)(c * CL + s) * BB + b;
#pragma unroll
        for (int m = 0; m < 6; ++m) {
          const int n = tid + m * 256;
          const f16* wp = WhT + (size_t)n * HH;
          float a = 0.f;
          for (int k8 = 0; k8 < 64; ++k8) {
            f16x8 w8 = *(const f16x8*)(wp + k8 * 8);
#pragma unroll
            for (int u = 0; u < 8; ++u) a += (float)w8[u] * hs[k8 * 8 + u];
          }
          gh[n] = a;
        }
        __syncthreads();
        for (int j = tid; j < HH; j += 256) {
          const float rr = sigf((float)gi[girow * HH + j] + gh[j]);
          const float zz = sigf((float)gi[PL + girow * HH + j] + gh[HH + j]);
          const float nn =
              tanhf((float)gi[2 * PL + girow * HH + j] + rr * (gh[2 * HH + j] + bhn[j]));
          const float hnew = (1.f - zz) * nn + zz * hs[j];
          out[girow * HH + j] = hnew;
          hs[j] = hnew;
        }
        __syncthreads();
      }
    }
  }
}

// --------------------------------------------------------------- k_phase3 ----
// Prefix fixup, launch per s: rows with fr > s (first cnt_gt[s] of fr-sorted
// list). 16 gathered rows per block; full 3-gate GEMM vs WhT from L2.
__global__ __launch_bounds__(256) void k_phase3(
    int s, const int* __restrict__ cnt, const int* __restrict__ list,
    const f16* __restrict__ WhT, const f16* __restrict__ gi,
    const float* __restrict__ bhn, float* __restrict__ out,
    f16* __restrict__ hph) {
  const int count = cnt[16 + s];
  const int r0 = blockIdx.x * 16;
  if (r0 >= count) return;
  __shared__ __align__(16) f16 As[16 * 520];
  __shared__ int rows[16];
  const int tid = threadIdx.x;
  const int lane = tid & 63;
  const int w = tid >> 6;
  if (tid < 16) rows[tid] = (r0 + tid < count) ? list[r0 + tid] : -1;
  __syncthreads();
#pragma unroll
  for (int uu = 0; uu < 4; ++uu) {
    int u = tid + uu * 256;
    int row = u >> 6, oc = (u & 63) * 8;
    int rid = rows[row];
    f16x8 v = {};
    if (rid >= 0) v = *(const f16x8*)(hph + (size_t)rid * HH + oc);
    *(f16x8*)&As[row * 520 + oc] = v;
  }
  __syncthreads();
  const int fr16 = lane & 15;
  const int q8 = (lane >> 4) * 8;
  const int trow = (lane >> 4) * 4;
  for (int jt = 0; jt < 8; ++jt) {
    const int jb = w * 128 + jt * 16;
    f32x4 a0 = {}, a1 = {}, a2 = {};
#pragma unroll 4
    for (int kb = 0; kb < 16; ++kb) {
      const int k0 = kb * 32;
      f16x8 af = *(const f16x8*)&As[fr16 * 520 + k0 + q8];
      f16x8 b0 = *(const f16x8*)(WhT + ((size_t)(jb + fr16)) * HH + k0 + q8);
      f16x8 b1 = *(const f16x8*)(WhT + ((size_t)(HH + jb + fr16)) * HH + k0 + q8);
      f16x8 b2 = *(const f16x8*)(WhT + ((size_t)(2 * HH + jb + fr16)) * HH + k0 + q8);
      a0 = __builtin_amdgcn_mfma_f32_16x16x32_f16(af, b0, a0, 0, 0, 0);
      a1 = __builtin_amdgcn_mfma_f32_16x16x32_f16(af, b1, a1, 0, 0, 0);
      a2 = __builtin_amdgcn_mfma_f32_16x16x32_f16(af, b2, a2, 0, 0, 0);
    }
    const int j = jb + fr16;
    const float bh = bhn[j];
#pragma unroll
    for (int r = 0; r < 4; ++r) {
      const int rid = rows[trow + r];
      if (rid < 0) continue;
      const int c = rid >> 7, b = rid & 127;
      const size_t girow = (size_t)(c * CL + s) * BB + b;
      const float gr = (float)gi[girow * HH + j];
      const float gz = (float)gi[PL + girow * HH + j];
      const float gn = (float)gi[2 * PL + girow * HH + j];
      const float hp = (float)hph[(size_t)rid * HH + j];
      const float rr = sigf(gr + a0[r]);
      const float zz = sigf(gz + a1[r]);
      const float nn = tanhf(gn + rr * (a2[r] + bh));
      const float hnew = (1.f - zz) * nn + zz * hp;
      out[girow * HH + j] = hnew;
      hph[(size_t)rid * HH + j] = (f16)hnew;
    }
  }
}

// ---------------------------------------------------------------------------
extern "C" void kernel_launch(void* const* d_in, const int* in_sizes, int n_in,
                              void* d_out, int out_size, void* d_ws, size_t ws_size,
                              hipStream_t stream) {
  const float* x = (const float*)d_in[0];
  const int* resets = (const int*)d_in[1];
  const float* Wi = (const float*)d_in[2];
  const float* bi = (const float*)d_in[3];
  const float* Wh = (const float*)d_in[4];
  const float* bhn = (const float*)d_in[5];
  const float* h0 = (const float*)d_in[6];
  float* out = (float*)d_out;

  char* ws = (char*)d_ws;
  size_t off = 0;
  f16* gi = (f16*)(ws + off);   off += 3 * PL * sizeof(f16);            // 201.3 MB
  f16* WiT = (f16*)(ws + off);  off += (size_t)HH * H3 * sizeof(f16);
  f16* WhT = (f16*)(ws + off);  off += (size_t)HH * H3 * sizeof(f16);
  f16* hA = (f16*)(ws + off);   off += (size_t)NR * HH * sizeof(f16);   // 8.4 MB
  f16* hB = (f16*)(ws + off);   off += (size_t)NR * HH * sizeof(f16);
  f16* hin = (f16*)(ws + off);  off += (size_t)NR * HH * sizeof(f16);
  int* fr = (int*)(ws + off);   off += NR * sizeof(int);
  int* list = (int*)(ws + off); off += NR * sizeof(int);
  int* cnt = (int*)(ws + off);  off += 64 * sizeof(int);
  (void)ws_size; (void)in_sizes; (void)n_in; (void)out_size;

  hipMemsetAsync(cnt, 0, 64 * sizeof(int), stream);
  k_prep<<<dim3(3072), 256, 0, stream>>>(Wi, Wh, resets, WiT, WhT, fr, cnt);
  k_sort<<<dim3(1), 1, 0, stream>>>(cnt);
  k_scatter<<<dim3(32), 256, 0, stream>>>(fr, cnt, list);
  k_gemm_gi<<<dim3(TBR / 64, H3 / 64), 256, 0, stream>>>(x, WiT, bi, gi);
  k_step0<<<dim3(NR * 64 / 256), 256, 0, stream>>>(resets, gi, bhn, out, hA);
  // phase 1: s=1..7; ping-pong: s odd reads hA writes hB, s even reads hB
  for (int s = 1; s < CL; ++s) {
    const f16* hrd = (s & 1) ? hA : hB;
    f16* hwr = (s & 1) ? hB : hA;
    k_phase1<<<dim3(NC, 8), 256, 0, stream>>>(s, resets, WhT, gi, bhn, out, hrd, hwr);
  }
  // chunk-end h = buffer written at s=7 (odd) = hB
  k_phase2<<<dim3(BB), 256, 0, stream>>>(fr, hB, WhT, gi, bhn, h0, out, hin);
  for (int s = 0; s < CL; ++s)
    k_phase3<<<dim3(NR / 16), 256, 0, stream>>>(s, cnt, list, WhT, gi, bhn, out, hin);
}